// Round 16
// baseline (449.543 us; speedup 1.0000x reference)
//
#include <hip/hip_runtime.h>
#include <hip/hip_bf16.h>

#define HH 256
#define SS 128
#define BB 8
#define MM 128
#define DD 256
#define TT 256
#define GG 16   // rows per edge WG
#define NW 8    // waves per WG

// scale folded into tanh-feeding weights: tanh(x) = 1 - 2/(exp2(S*x)+1), S = 2*log2(e)
#define TSC 2.885390081777927f

// fragment-layout LDS: row stride 33 groups of 16B (odd -> conflict-minimal)
#define ROWG 33
#define FBE (16 * ROWG * 8)  // ushorts per 16-row phase buffer (edge)
#define FB1 (ROWG * 8)       // ushorts per 1-row phase buffer (graph)

typedef float  f32x4  __attribute__((ext_vector_type(4)));
typedef short  bf16x8 __attribute__((ext_vector_type(8)));

__device__ __forceinline__ float bflo(unsigned int u) { return __uint_as_float(u << 16); }
__device__ __forceinline__ float bfhi(unsigned int u) { return __uint_as_float(u & 0xffff0000u); }
__device__ __forceinline__ float bfs(unsigned short s) { return __uint_as_float(((unsigned)s) << 16); }
__device__ __forceinline__ unsigned short f2bf(float x) {
    unsigned u = __float_as_uint(x);
    return (unsigned short)((u + 0x7fffu + ((u >> 16) & 1u)) >> 16);
}
// HW packed f32x2 -> bf16x2 (RNE), 1 VALU op
__device__ __forceinline__ unsigned cvtpk(float lo, float hi) {
    unsigned r;
    asm("v_cvt_pk_bf16_f32 %0, %1, %2" : "=v"(r) : "v"(lo), "v"(hi));
    return r;
}
// tanh on PRE-SCALED input (x already multiplied by TSC upstream); exp2f is
// compiler-lowered to v_exp_f32 with proper hazard handling (no inline asm).
__device__ __forceinline__ float ftanh_s(float x) {
    return 1.0f - 2.0f * __builtin_amdgcn_rcpf(exp2f(x) + 1.0f);
}
__device__ __forceinline__ float fsigm(float x) {
    return __builtin_amdgcn_rcpf(1.0f + __expf(-x));
}

// ---------------- fused prep: 8 weight packs + eW_ih0 transpose->bf16 ----------------
// matrices m<6 (tanh-feeding) are scaled by TSC; head/dep (m=6,7) unscaled.
__global__ void k_prep(const float* __restrict__ gW_hh0, const float* __restrict__ gW_ih1,
                       const float* __restrict__ gW_hh1, const float* __restrict__ eW_hh0,
                       const float* __restrict__ eW_ih1, const float* __restrict__ eW_hh1,
                       const float* __restrict__ head_W, const float* __restrict__ dep_W,
                       const float* __restrict__ eW_ih0,
                       unsigned short* __restrict__ pk_g0, unsigned short* __restrict__ pk_g1,
                       unsigned short* __restrict__ pk_g2, unsigned short* __restrict__ pk_e0,
                       unsigned short* __restrict__ pk_e1, unsigned short* __restrict__ pk_e2,
                       unsigned short* __restrict__ pk_h0, unsigned short* __restrict__ pk_h1,
                       unsigned short* __restrict__ eWTb) {
    int m = blockIdx.x >> 5;
    int blk = blockIdx.x & 31;
    if (m < 8) {
        const float* W = (m == 0) ? gW_hh0 : (m == 1) ? gW_ih1 : (m == 2) ? gW_hh1
                       : (m == 3) ? eW_hh0 : (m == 4) ? eW_ih1 : (m == 5) ? eW_hh1
                       : (m == 6) ? head_W : dep_W;
        unsigned short* pk = (m == 0) ? pk_g0 : (m == 1) ? pk_g1 : (m == 2) ? pk_g2
                           : (m == 3) ? pk_e0 : (m == 4) ? pk_e1 : (m == 5) ? pk_e2
                           : (m == 6) ? pk_h0 : pk_h1;
        float sc = (m < 6) ? TSC : 1.0f;
        int idx = blk * 256 + threadIdx.x;      // 8192 = 128 frags * 64 lanes
        int f = idx >> 6, l = idx & 63;
        int ct = f >> 3, kb = f & 7, q = l >> 4, mm = l & 15;
        unsigned short out[8];
#pragma unroll
        for (int e = 0; e < 8; e++) {
            int k = kb * 32 + q * 4 + (e & 3) + ((e >> 2) << 4);
            out[e] = f2bf(sc * W[(ct * 16 + mm) * HH + k]);
        }
        uint4 v;
        v.x = out[0] | ((unsigned)out[1] << 16);
        v.y = out[2] | ((unsigned)out[3] << 16);
        v.z = out[4] | ((unsigned)out[5] << 16);
        v.w = out[6] | ((unsigned)out[7] << 16);
        *(uint4*)(pk + idx * 8) = v;
    } else {
        int base = blk * 256 + threadIdx.x;
#pragma unroll
        for (int k = 0; k < 4; k++) {
            int idx = base + k * 8192;
            int j = idx >> 8, c = idx & 255;
            eWTb[idx] = f2bf(TSC * eW_ih0[c * MM + j]);
        }
    }
}

// ---------------- X0B[b][t][i] = bf16(TSC * (input @ gW_ih0^T + gb_ih0 + gb_hh0)) --------
__global__ void k_x0(const float* __restrict__ x, const float* __restrict__ Wih0,
                     const float* __restrict__ bih0, const float* __restrict__ bhh0,
                     unsigned short* __restrict__ X0B) {
    int row = blockIdx.x;           // b*SS + t
    int i = threadIdx.x;
    const float4* xr = (const float4*)(x + row * DD);
    const float4* wr = (const float4*)(Wih0 + i * DD);
    float a0 = 0.f, a1 = 0.f, a2 = 0.f, a3 = 0.f;
#pragma unroll 8
    for (int k = 0; k < DD / 4; k++) {
        float4 xv = xr[k]; float4 wv = wr[k];
        a0 += xv.x * wv.x; a1 += xv.y * wv.y; a2 += xv.z * wv.z; a3 += xv.w * wv.w;
    }
    X0B[row * HH + i] = f2bf(TSC * (a0 + a1 + a2 + a3 + bih0[i] + bhh0[i]));
}

// ---------------- MFMA fragment loaders ----------------
__device__ __forceinline__ bf16x8 ldA(const unsigned short* __restrict__ pk, int ct, int kb, int lane) {
    return *(const bf16x8*)(pk + (((ct * 8 + kb) * 64 + lane) << 3));
}
__device__ __forceinline__ bf16x8 ldBf(const unsigned short* base, int row, int kb, int q) {
    return *(const bf16x8*)(base + ((row * ROWG + kb * 4 + q) << 3));
}

// ---------------- graph RNN: one WG per batch; CRITICAL-FIRST phase order ----------------
__global__ __launch_bounds__(512, 2) void k_graph_mfma(
    const unsigned short* __restrict__ X0B, const int* __restrict__ mask,
    const unsigned short* __restrict__ pk0,  // gW_hh0 packed (scaled)
    const unsigned short* __restrict__ pk1,  // gW_ih1 packed (scaled)
    const unsigned short* __restrict__ pk2,  // gW_hh1 packed (scaled)
    const float* __restrict__ bih1, const float* __restrict__ bhh1,
    float* __restrict__ GS) {
    __shared__ alignas(16) unsigned short xs[SS * HH];   // 64 KB: X0 bf16
    __shared__ alignas(16) unsigned short gs[SS * HH];   // 64 KB: GS bf16
    __shared__ alignas(16) unsigned short h0b[2 * FB1];
    __shared__ alignas(16) unsigned short h1b[3 * FB1];
    __shared__ int lenS;

    int b = blockIdx.x;
    int tid = threadIdx.x;
    int wv = tid >> 6, lane = tid & 63;
    int q = lane >> 4, rr = lane & 15;
    int ct0 = 2 * wv;
    int m0 = 32 * wv + 4 * q;
    int g16off = (wv * 4 + q) << 3;

    { unsigned* p = (unsigned*)h0b; for (int i = tid; i < FB1; i += 512) p[i] = 0; }
    { unsigned* p = (unsigned*)h1b; for (int i = tid; i < 3 * FB1 / 2; i += 512) p[i] = 0; }
    {
        const uint4* s = (const uint4*)(X0B + b * SS * HH);
        uint4* d = (uint4*)xs;
        for (int i = tid; i < SS * HH / 8; i += 512) d[i] = s[i];
    }
    if (wv == 0) {
        int s = mask[b * SS + lane] + mask[b * SS + 64 + lane];
        for (int off = 32; off; off >>= 1) s += __shfl_xor(s, off);
        if (lane == 0) lenS = s;
    }
    bf16x8 a0[2][8], a1[2][8], a2[2][8];
#pragma unroll
    for (int kb = 0; kb < 8; kb++) {
        a0[0][kb] = ldA(pk0, ct0, kb, lane); a0[1][kb] = ldA(pk0, ct0 + 1, kb, lane);
        a1[0][kb] = ldA(pk1, ct0, kb, lane); a1[1][kb] = ldA(pk1, ct0 + 1, kb, lane);
        a2[0][kb] = ldA(pk2, ct0, kb, lane); a2[1][kb] = ldA(pk2, ct0 + 1, kb, lane);
    }
#pragma unroll
    for (int kb = 0; kb < 8; kb++) {
        asm volatile("" : "+v"(a0[0][kb]), "+v"(a0[1][kb]),
                          "+v"(a1[0][kb]), "+v"(a1[1][kb]),
                          "+v"(a2[0][kb]), "+v"(a2[1][kb]));
    }
    f32x4 b1A = (*(const f32x4*)(bih1 + m0) + *(const f32x4*)(bhh1 + m0)) * TSC;
    f32x4 b1B = (*(const f32x4*)(bih1 + m0 + 16) + *(const f32x4*)(bhh1 + m0 + 16)) * TSC;
    __syncthreads();
    int len = lenS;                 // WG-uniform, len >= 64
    bool w0l = (rr == 0);

    // ---- phase 0: h0[0] = tanh(x[0]) ----
    {
        ushort4 xa = *(const ushort4*)(xs + m0);
        ushort4 xb = *(const ushort4*)(xs + m0 + 16);
        if (w0l) {
            uint4 nv = { cvtpk(ftanh_s(bfs(xa.x)), ftanh_s(bfs(xa.y))),
                         cvtpk(ftanh_s(bfs(xa.z)), ftanh_s(bfs(xa.w))),
                         cvtpk(ftanh_s(bfs(xb.x)), ftanh_s(bfs(xb.y))),
                         cvtpk(ftanh_s(bfs(xb.z)), ftanh_s(bfs(xb.w))) };
            *(uint4*)(h0b + g16off) = nv;
        }
    }
    __syncthreads();

    // x prefetch for t=1
    ushort4 xcA = *(const ushort4*)(xs + 256 + m0);
    ushort4 xcB = *(const ushort4*)(xs + 256 + m0 + 16);

    // ---- main phases t=1..len-1: h0[t] (critical-first) then h1[t-1]; 1 barrier ----
    int ir = 2, iw = 0;
    for (int t = 1; t < len; t++) {
        const unsigned short* h0r = h0b + ((t - 1) & 1) * FB1;
        const unsigned short* h1r = h1b + ir * FB1;
        int tn = (t + 1 < SS) ? t + 1 : t;
        ushort4 xnA = *(const ushort4*)(xs + tn * 256 + m0);
        ushort4 xnB = *(const ushort4*)(xs + tn * 256 + m0 + 16);
        f32x4 accA0 = { bfs(xcA.x), bfs(xcA.y), bfs(xcA.z), bfs(xcA.w) };
        f32x4 accB0 = { bfs(xcB.x), bfs(xcB.y), bfs(xcB.z), bfs(xcB.w) };
        f32x4 accA1 = {0.f,0.f,0.f,0.f}, accB1 = {0.f,0.f,0.f,0.f};
        f32x4 pAe = b1A, pBe = b1B;
        // ---- part 1: consume h0[t-1] frags (8 reads), acc + L1-e MFMAs ----
#pragma unroll
        for (int kb = 0; kb < 4; kb++) {
            bf16x8 h = ldBf(h0r, 0, kb, q);
            accA0 = __builtin_amdgcn_mfma_f32_16x16x32_bf16(a0[0][kb], h, accA0, 0, 0, 0);
            accB0 = __builtin_amdgcn_mfma_f32_16x16x32_bf16(a0[1][kb], h, accB0, 0, 0, 0);
            pAe   = __builtin_amdgcn_mfma_f32_16x16x32_bf16(a1[0][kb], h, pAe, 0, 0, 0);
            pBe   = __builtin_amdgcn_mfma_f32_16x16x32_bf16(a1[1][kb], h, pBe, 0, 0, 0);
        }
#pragma unroll
        for (int kb = 4; kb < 8; kb++) {
            bf16x8 h = ldBf(h0r, 0, kb, q);
            accA1 = __builtin_amdgcn_mfma_f32_16x16x32_bf16(a0[0][kb], h, accA1, 0, 0, 0);
            accB1 = __builtin_amdgcn_mfma_f32_16x16x32_bf16(a0[1][kb], h, accB1, 0, 0, 0);
            pAe   = __builtin_amdgcn_mfma_f32_16x16x32_bf16(a1[0][kb], h, pAe, 0, 0, 0);
            pBe   = __builtin_amdgcn_mfma_f32_16x16x32_bf16(a1[1][kb], h, pBe, 0, 0, 0);
        }
        if (w0l) {
            f32x4 accA = accA0 + accA1, accB = accB0 + accB1;
            uint4 nv0 = { cvtpk(ftanh_s(accA[0]), ftanh_s(accA[1])), cvtpk(ftanh_s(accA[2]), ftanh_s(accA[3])),
                          cvtpk(ftanh_s(accB[0]), ftanh_s(accB[1])), cvtpk(ftanh_s(accB[2]), ftanh_s(accB[3])) };
            *(uint4*)(h0b + (t & 1) * FB1 + g16off) = nv0;
        }
        // ---- part 2: consume h1[t-2] frags (8 reads), L1-h MFMAs, finish h1[t-1] ----
        f32x4 pAh = {0.f,0.f,0.f,0.f}, pBh = {0.f,0.f,0.f,0.f};
#pragma unroll
        for (int kb = 0; kb < 8; kb++) {
            bf16x8 g = ldBf(h1r, 0, kb, q);
            pAh = __builtin_amdgcn_mfma_f32_16x16x32_bf16(a2[0][kb], g, pAh, 0, 0, 0);
            pBh = __builtin_amdgcn_mfma_f32_16x16x32_bf16(a2[1][kb], g, pBh, 0, 0, 0);
        }
        if (w0l) {
            f32x4 pA = pAe + pAh, pB = pBe + pBh;
            float eA[4], eB[4];
#pragma unroll
            for (int r = 0; r < 4; r++) { eA[r] = ftanh_s(pA[r]); eB[r] = ftanh_s(pB[r]); }
            uint4 nv1 = { cvtpk(eA[0], eA[1]), cvtpk(eA[2], eA[3]),
                          cvtpk(eB[0], eB[1]), cvtpk(eB[2], eB[3]) };
            *(uint4*)(h1b + iw * FB1 + g16off) = nv1;
            uint2 ga = { cvtpk(eA[0], eA[1]), cvtpk(eA[2], eA[3]) };
            uint2 gb = { cvtpk(eB[0], eB[1]), cvtpk(eB[2], eB[3]) };
            *(uint2*)(gs + (t - 1) * 256 + m0) = ga;
            *(uint2*)(gs + (t - 1) * 256 + m0 + 16) = gb;
        }
        __syncthreads();
        xcA = xnA; xcB = xnB;
        ir = (ir + 1 == 3) ? 0 : ir + 1;
        iw = (iw + 1 == 3) ? 0 : iw + 1;
    }

    // ---- tail: h1[len-1] -> gs[len-1] ----
    {
        const unsigned short* h0r = h0b + ((len - 1) & 1) * FB1;
        const unsigned short* h1r = h1b + ir * FB1;
        f32x4 pAe = b1A, pBe = b1B;
        f32x4 pAh = {0.f,0.f,0.f,0.f}, pBh = {0.f,0.f,0.f,0.f};
#pragma unroll
        for (int kb = 0; kb < 8; kb++) {
            bf16x8 h = ldBf(h0r, 0, kb, q);
            bf16x8 g = ldBf(h1r, 0, kb, q);
            pAe = __builtin_amdgcn_mfma_f32_16x16x32_bf16(a1[0][kb], h, pAe, 0, 0, 0);
            pBe = __builtin_amdgcn_mfma_f32_16x16x32_bf16(a1[1][kb], h, pBe, 0, 0, 0);
            pAh = __builtin_amdgcn_mfma_f32_16x16x32_bf16(a2[0][kb], g, pAh, 0, 0, 0);
            pBh = __builtin_amdgcn_mfma_f32_16x16x32_bf16(a2[1][kb], g, pBh, 0, 0, 0);
        }
        if (w0l) {
            f32x4 pA = pAe + pAh, pB = pBe + pBh;
            uint2 ga = { cvtpk(ftanh_s(pA[0]), ftanh_s(pA[1])), cvtpk(ftanh_s(pA[2]), ftanh_s(pA[3])) };
            uint2 gb = { cvtpk(ftanh_s(pB[0]), ftanh_s(pB[1])), cvtpk(ftanh_s(pB[2]), ftanh_s(pB[3])) };
            *(uint2*)(gs + (len - 1) * 256 + m0) = ga;
            *(uint2*)(gs + (len - 1) * 256 + m0 + 16) = gb;
        }
    }
    __syncthreads();
    // ---- flush gs -> GS (f32), zeros for t >= len ----
    {
        float* dst = GS + b * (SS * HH);
        const uint4* src = (const uint4*)gs;
        for (int i = tid; i < SS * HH / 8; i += 512) {
            int t = i >> 5;
            float4 f0 = {0.f,0.f,0.f,0.f}, f1 = {0.f,0.f,0.f,0.f};
            if (t < len) {
                uint4 v = src[i];
                f0 = float4{ bflo(v.x), bfhi(v.x), bflo(v.y), bfhi(v.y) };
                f1 = float4{ bflo(v.z), bfhi(v.z), bflo(v.w), bfhi(v.w) };
            }
            *(float4*)(dst + i * 8) = f0;
            *(float4*)(dst + i * 8 + 4) = f1;
        }
    }
}

// ---------------- edge RNN scan: MERGED phases (R14 structure, no prefetch) ----------
__global__ __launch_bounds__(512, 2) void k_edge_mfma(
    const float* __restrict__ GS,
    const unsigned short* __restrict__ pk0,  // eW_hh0 packed (scaled)
    const unsigned short* __restrict__ pk1,  // eW_ih1 packed (scaled)
    const unsigned short* __restrict__ pk2,  // eW_hh1 packed (scaled)
    const unsigned short* __restrict__ pkh,  // head_W packed
    const unsigned short* __restrict__ pkd,  // dep_W packed
    const unsigned short* __restrict__ eWTb, // eW_ih0^T bf16 (scaled)
    const float* __restrict__ bih0, const float* __restrict__ bhh0,
    const float* __restrict__ bih1, const float* __restrict__ bhh1,
    const float* __restrict__ clsW, const float* __restrict__ clsB,
    const float* __restrict__ headB, const float* __restrict__ depB,
    float* __restrict__ arc, float* __restrict__ headO, float* __restrict__ depO) {
    __shared__ alignas(16) unsigned short h0f[2 * FBE];
    __shared__ alignas(16) unsigned short h1f[2 * FBE];
    __shared__ alignas(16) unsigned short gsf[FBE];      // GS init frags (for heads)
    __shared__ alignas(16) unsigned short ews[MM * HH];  // 64 KB
    __shared__ alignas(16) float red[GG][NW];
    __shared__ float cws[HH];
    __shared__ float b1s[HH];
    __shared__ float arcb[GG][MM + 1];

    int tid = threadIdx.x;
    int wv = tid >> 6, lane = tid & 63;
    int q = lane >> 4, rr = lane & 15;
    int m0 = 32 * wv + 4 * q;
    int goff = (rr * ROWG + wv * 4 + q) << 3;
    int r0 = blockIdx.x * GG;

    // stage eWTb into LDS (64 KB coalesced)
    {
        const uint4* s = (const uint4*)eWTb;
        uint4* d = (uint4*)ews;
        for (int i = tid; i < MM * HH / 8; i += 512) d[i] = s[i];
    }
    // init: h0[-1]=h1[-1]=gsf (buf 1); zero buf 0 (phase-0 dummy h1[-2] reads)
    {
        int r = tid >> 5, g = tid & 31;           // g = kb*4 + qq
        int kb = g >> 2, qq = g & 3;
        int lo = kb * 32 + qq * 4;
        const float* gp = GS + (r0 + r) * HH + lo;
        float4 vlo = *(const float4*)gp;
        float4 vhi = *(const float4*)(gp + 16);
        uint4 pv = { cvtpk(vlo.x, vlo.y), cvtpk(vlo.z, vlo.w),
                     cvtpk(vhi.x, vhi.y), cvtpk(vhi.z, vhi.w) };
        int off = (r * ROWG + g) << 3;
        *(uint4*)(h0f + FBE + off) = pv;
        *(uint4*)(h1f + FBE + off) = pv;
        *(uint4*)(gsf + off) = pv;
        *(uint4*)(h1f + off) = uint4{0,0,0,0};
        *(uint4*)(h0f + off) = uint4{0,0,0,0};
    }
    if (tid < HH) {
        cws[tid] = clsW[tid];
        b1s[tid] = TSC * (bih1[tid] + bhh1[tid]);
    }
    // weights -> registers (192/lane), pinned
    bf16x8 a0[2][8], a1[2][8], a2[2][8];
#pragma unroll
    for (int kb = 0; kb < 8; kb++) {
        a0[0][kb] = ldA(pk0, 2 * wv, kb, lane); a0[1][kb] = ldA(pk0, 2 * wv + 1, kb, lane);
        a1[0][kb] = ldA(pk1, 2 * wv, kb, lane); a1[1][kb] = ldA(pk1, 2 * wv + 1, kb, lane);
        a2[0][kb] = ldA(pk2, 2 * wv, kb, lane); a2[1][kb] = ldA(pk2, 2 * wv + 1, kb, lane);
    }
#pragma unroll
    for (int kb = 0; kb < 8; kb++) {
        asm volatile("" : "+v"(a0[0][kb]), "+v"(a0[1][kb]),
                          "+v"(a1[0][kb]), "+v"(a1[1][kb]),
                          "+v"(a2[0][kb]), "+v"(a2[1][kb]));
    }
    // xw0 in registers (D-layout, pre-scaled)
    f32x4 xw0A = (*(const f32x4*)(bih0 + m0) + *(const f32x4*)(bhh0 + m0)) * TSC;
    f32x4 xw0B = (*(const f32x4*)(bih0 + m0 + 16) + *(const f32x4*)(bhh0 + m0 + 16)) * TSC;
    float clsb = clsB[0];
    int srow = (r0 + tid) & 127;
    __syncthreads();

    for (int j = 0; j <= MM; j++) {
        const unsigned short* h0r = h0f + ((j + 1) & 1) * FBE;   // h0[j-1]
        const unsigned short* h1r = h1f + (j & 1) * FBE;         // h1[j-2]
        f32x4 acc0 = xw0A, acc1 = xw0B;                  // layer0[j]
        f32x4 p0 = *(const f32x4*)&b1s[m0];              // layer1[j-1]
        f32x4 p1 = *(const f32x4*)&b1s[m0 + 16];
#pragma unroll
        for (int kb = 0; kb < 8; kb++) {
            bf16x8 b0 = ldBf(h0r, rr, kb, q);            // shared: L0 + L1-e
            bf16x8 b1 = ldBf(h1r, rr, kb, q);
            acc0 = __builtin_amdgcn_mfma_f32_16x16x32_bf16(a0[0][kb], b0, acc0, 0, 0, 0);
            acc1 = __builtin_amdgcn_mfma_f32_16x16x32_bf16(a0[1][kb], b0, acc1, 0, 0, 0);
            p0   = __builtin_amdgcn_mfma_f32_16x16x32_bf16(a1[0][kb], b0, p0, 0, 0, 0);
            p1   = __builtin_amdgcn_mfma_f32_16x16x32_bf16(a1[1][kb], b0, p1, 0, 0, 0);
            p0   = __builtin_amdgcn_mfma_f32_16x16x32_bf16(a2[0][kb], b1, p0, 0, 0, 0);
            p1   = __builtin_amdgcn_mfma_f32_16x16x32_bf16(a2[1][kb], b1, p1, 0, 0, 0);
        }
        if (j > 0) {
            float e1a[4], e1b[4];
#pragma unroll
            for (int r = 0; r < 4; r++) { e1a[r] = ftanh_s(p0[r]); e1b[r] = ftanh_s(p1[r]); }
            // h1[j-1] frag write
            uint4 nv = { cvtpk(e1a[0], e1a[1]), cvtpk(e1a[2], e1a[3]),
                         cvtpk(e1b[0], e1b[1]), cvtpk(e1b[2], e1b[3]) };
            *(uint4*)(h1f + ((j + 1) & 1) * FBE + goff) = nv;
            // cls partial, reduce over q
            f32x4 cwA = *(const f32x4*)&cws[m0];
            f32x4 cwB = *(const f32x4*)&cws[m0 + 16];
            float part = cwA[0] * e1a[0] + cwA[1] * e1a[1] + cwA[2] * e1a[2] + cwA[3] * e1a[3]
                       + cwB[0] * e1b[0] + cwB[1] * e1b[1] + cwB[2] * e1b[2] + cwB[3] * e1b[3];
            part += __shfl_xor(part, 16);
            part += __shfl_xor(part, 32);
            if (lane < 16) red[lane][wv] = part;
        }
        __syncthreads();   // B1: red + h1[j-1] complete
        if (j > 0) {
            f32x4 r0v = *(const f32x4*)&red[rr][0];
            f32x4 r1v = *(const f32x4*)&red[rr][4];
            float s = clsb + r0v[0] + r0v[1] + r0v[2] + r0v[3]
                           + r1v[0] + r1v[1] + r1v[2] + r1v[3];
            float edge = fsigm(s);
            ushort4 ewcA = *(const ushort4*)(ews + (j - 1) * HH + m0);
            ushort4 ewcB = *(const ushort4*)(ews + (j - 1) * HH + m0 + 16);
            f32x4 ewA = { bfs(ewcA.x), bfs(ewcA.y), bfs(ewcA.z), bfs(ewcA.w) };
            f32x4 ewB = { bfs(ewcB.x), bfs(ewcB.y), bfs(ewcB.z), bfs(ewcB.w) };
            xw0A += edge * ewA;  acc0 += edge * ewA;     // linear fix-up for col j-1
            xw0B += edge * ewB;  acc1 += edge * ewB;
            if (tid < GG) arcb[tid][j - 1] = ((j - 1) < srow) ? edge : 0.f;
        }
        if (j < MM) {
            uint4 nv = { cvtpk(ftanh_s(acc0[0]), ftanh_s(acc0[1])), cvtpk(ftanh_s(acc0[2]), ftanh_s(acc0[3])),
                         cvtpk(ftanh_s(acc1[0]), ftanh_s(acc1[1])), cvtpk(ftanh_s(acc1[2]), ftanh_s(acc1[3])) };
            *(uint4*)(h0f + (j & 1) * FBE + goff) = nv;
        }
        __syncthreads();   // B2: h0[j] complete
    }
    // ---- flush arc buffer ----
    for (int i = tid; i < GG * MM; i += 512) {
        int row = i & 15, j = i >> 4;
        int sr = (r0 + row) & 127, bi = (r0 + row) >> 7;
        arc[bi * (MM * SS) + j * SS + sr] = arcb[row][j];
    }
    // ---- fused heads: elu(GS @ W^T + b) via MFMA on gsf (unroll 1 -> no reg blowup) ----
    {
        f32x4 hA = *(const f32x4*)(headB + m0);
        f32x4 hB = *(const f32x4*)(headB + m0 + 16);
        f32x4 dA = *(const f32x4*)(depB + m0);
        f32x4 dB = *(const f32x4*)(depB + m0 + 16);
#pragma unroll 1
        for (int kb = 0; kb < 8; kb++) {
            bf16x8 bg = ldBf(gsf, rr, kb, q);
            hA = __builtin_amdgcn_mfma_f32_16x16x32_bf16(ldA(pkh, 2 * wv, kb, lane), bg, hA, 0, 0, 0);
            hB = __builtin_amdgcn_mfma_f32_16x16x32_bf16(ldA(pkh, 2 * wv + 1, kb, lane), bg, hB, 0, 0, 0);
            dA = __builtin_amdgcn_mfma_f32_16x16x32_bf16(ldA(pkd, 2 * wv, kb, lane), bg, dA, 0, 0, 0);
            dB = __builtin_amdgcn_mfma_f32_16x16x32_bf16(ldA(pkd, 2 * wv + 1, kb, lane), bg, dB, 0, 0, 0);
        }
        int row = r0 + rr;
        f32x4 oA, oB, eA, eB;
#pragma unroll
        for (int r = 0; r < 4; r++) {
            oA[r] = (hA[r] > 0.f) ? hA[r] : (__expf(hA[r]) - 1.0f);
            oB[r] = (hB[r] > 0.f) ? hB[r] : (__expf(hB[r]) - 1.0f);
            eA[r] = (dA[r] > 0.f) ? dA[r] : (__expf(dA[r]) - 1.0f);
            eB[r] = (dB[r] > 0.f) ? dB[r] : (__expf(dB[r]) - 1.0f);
        }
        *(f32x4*)(headO + row * TT + m0) = oA;
        *(f32x4*)(headO + row * TT + m0 + 16) = oB;
        *(f32x4*)(depO + row * TT + m0) = eA;
        *(f32x4*)(depO + row * TT + m0 + 16) = eB;
    }
}

extern "C" void kernel_launch(void* const* d_in, const int* in_sizes, int n_in,
                              void* d_out, int out_size, void* d_ws, size_t ws_size,
                              hipStream_t stream) {
    const float* input  = (const float*)d_in[0];
    const int*   mask   = (const int*)d_in[2];
    const float* gW_ih0 = (const float*)d_in[5];
    const float* gW_hh0 = (const float*)d_in[6];
    const float* gb_ih0 = (const float*)d_in[7];
    const float* gb_hh0 = (const float*)d_in[8];
    const float* gW_ih1 = (const float*)d_in[9];
    const float* gW_hh1 = (const float*)d_in[10];
    const float* gb_ih1 = (const float*)d_in[11];
    const float* gb_hh1 = (const float*)d_in[12];
    const float* eW_ih0 = (const float*)d_in[13];
    const float* eW_hh0 = (const float*)d_in[14];
    const float* eb_ih0 = (const float*)d_in[15];
    const float* eb_hh0 = (const float*)d_in[16];
    const float* eW_ih1 = (const float*)d_in[17];
    const float* eW_hh1 = (const float*)d_in[18];
    const float* eb_ih1 = (const float*)d_in[19];
    const float* eb_hh1 = (const float*)d_in[20];
    const float* cls_W  = (const float*)d_in[21];
    const float* cls_b  = (const float*)d_in[22];
    const float* head_W = (const float*)d_in[23];
    const float* head_b = (const float*)d_in[24];
    const float* dep_W  = (const float*)d_in[25];
    const float* dep_b  = (const float*)d_in[26];

    float* out      = (float*)d_out;
    float* head_out = out;                 // 8*128*256
    float* dep_out  = out + 262144;
    float* arc_out  = out + 524288;        // 8*128*128

    char* ws = (char*)d_ws;
    unsigned short* X0B = (unsigned short*)ws;                 // 512 KB bf16 [b][t][i]
    float* GS  = (float*)(ws + (1 << 20));                     // 1 MB
    unsigned short* pk_g0 = (unsigned short*)(ws + (2 << 20)); // 128 KB each
    unsigned short* pk_g1 = pk_g0 + 65536;
    unsigned short* pk_g2 = pk_g0 + 2 * 65536;
    unsigned short* pk_e0 = pk_g0 + 3 * 65536;
    unsigned short* pk_e1 = pk_g0 + 4 * 65536;
    unsigned short* pk_e2 = pk_g0 + 5 * 65536;
    unsigned short* pk_h0 = pk_g0 + 6 * 65536;
    unsigned short* pk_h1 = pk_g0 + 7 * 65536;
    unsigned short* eWTb  = pk_g0 + 8 * 65536;                 // 64 KB bf16

    k_prep<<<288, 256, 0, stream>>>(gW_hh0, gW_ih1, gW_hh1, eW_hh0, eW_ih1, eW_hh1,
                                    head_W, dep_W, eW_ih0,
                                    pk_g0, pk_g1, pk_g2, pk_e0, pk_e1, pk_e2,
                                    pk_h0, pk_h1, eWTb);
    k_x0<<<1024, 256, 0, stream>>>(input, gW_ih0, gb_ih0, gb_hh0, X0B);
    k_graph_mfma<<<8, 512, 0, stream>>>(X0B, mask, pk_g0, pk_g1, pk_g2, gb_ih1, gb_hh1, GS);
    k_edge_mfma<<<64, 512, 0, stream>>>(GS, pk_e0, pk_e1, pk_e2, pk_h0, pk_h1, eWTb,
                                        eb_ih0, eb_hh0, eb_ih1, eb_hh1, cls_W, cls_b,
                                        head_b, dep_b, arc_out, head_out, dep_out);
}

// Round 17
// 408.115 us; speedup vs baseline: 1.1015x; 1.1015x over previous
//
#include <hip/hip_runtime.h>
#include <hip/hip_bf16.h>

#define HH 256
#define SS 128
#define BB 8
#define MM 128
#define DD 256
#define TT 256
#define GG 16   // rows per edge WG
#define NW 8    // waves per WG

// fragment-layout LDS: row stride 33 groups of 16B (odd -> conflict-minimal)
#define ROWG 33
#define FBE (16 * ROWG * 8)  // ushorts per 16-row phase buffer (edge)
#define FB1 (ROWG * 8)       // ushorts per 1-row phase buffer (graph)

typedef float  f32x4  __attribute__((ext_vector_type(4)));
typedef short  bf16x8 __attribute__((ext_vector_type(8)));

__device__ __forceinline__ float bflo(unsigned int u) { return __uint_as_float(u << 16); }
__device__ __forceinline__ float bfhi(unsigned int u) { return __uint_as_float(u & 0xffff0000u); }
__device__ __forceinline__ float bfs(unsigned short s) { return __uint_as_float(((unsigned)s) << 16); }
__device__ __forceinline__ unsigned short f2bf(float x) {
    unsigned u = __float_as_uint(x);
    return (unsigned short)((u + 0x7fffu + ((u >> 16) & 1u)) >> 16);
}
// HW packed f32x2 -> bf16x2 (RNE), 1 VALU op (no builtin on gfx950 -> inline asm)
__device__ __forceinline__ unsigned cvtpk(float lo, float hi) {
    unsigned r;
    asm("v_cvt_pk_bf16_f32 %0, %1, %2" : "=v"(r) : "v"(lo), "v"(hi));
    return r;
}
__device__ __forceinline__ float ftanh(float x) {
    float e = __expf(2.0f * x);
    return 1.0f - 2.0f * __builtin_amdgcn_rcpf(e + 1.0f);
}
__device__ __forceinline__ float fsigm(float x) {
    return __builtin_amdgcn_rcpf(1.0f + __expf(-x));
}

// ---------------- fused prep: 8 weight packs + eW_ih0 transpose->bf16 ----------------
__global__ void k_prep(const float* __restrict__ gW_hh0, const float* __restrict__ gW_ih1,
                       const float* __restrict__ gW_hh1, const float* __restrict__ eW_hh0,
                       const float* __restrict__ eW_ih1, const float* __restrict__ eW_hh1,
                       const float* __restrict__ head_W, const float* __restrict__ dep_W,
                       const float* __restrict__ eW_ih0,
                       unsigned short* __restrict__ pk_g0, unsigned short* __restrict__ pk_g1,
                       unsigned short* __restrict__ pk_g2, unsigned short* __restrict__ pk_e0,
                       unsigned short* __restrict__ pk_e1, unsigned short* __restrict__ pk_e2,
                       unsigned short* __restrict__ pk_h0, unsigned short* __restrict__ pk_h1,
                       unsigned short* __restrict__ eWTb) {
    int m = blockIdx.x >> 5;
    int blk = blockIdx.x & 31;
    if (m < 8) {
        const float* W = (m == 0) ? gW_hh0 : (m == 1) ? gW_ih1 : (m == 2) ? gW_hh1
                       : (m == 3) ? eW_hh0 : (m == 4) ? eW_ih1 : (m == 5) ? eW_hh1
                       : (m == 6) ? head_W : dep_W;
        unsigned short* pk = (m == 0) ? pk_g0 : (m == 1) ? pk_g1 : (m == 2) ? pk_g2
                           : (m == 3) ? pk_e0 : (m == 4) ? pk_e1 : (m == 5) ? pk_e2
                           : (m == 6) ? pk_h0 : pk_h1;
        int idx = blk * 256 + threadIdx.x;      // 8192 = 128 frags * 64 lanes
        int f = idx >> 6, l = idx & 63;
        int ct = f >> 3, kb = f & 7, q = l >> 4, mm = l & 15;
        unsigned short out[8];
#pragma unroll
        for (int e = 0; e < 8; e++) {
            int k = kb * 32 + q * 4 + (e & 3) + ((e >> 2) << 4);
            out[e] = f2bf(W[(ct * 16 + mm) * HH + k]);
        }
        uint4 v;
        v.x = out[0] | ((unsigned)out[1] << 16);
        v.y = out[2] | ((unsigned)out[3] << 16);
        v.z = out[4] | ((unsigned)out[5] << 16);
        v.w = out[6] | ((unsigned)out[7] << 16);
        *(uint4*)(pk + idx * 8) = v;
    } else {
        int base = blk * 256 + threadIdx.x;
#pragma unroll
        for (int k = 0; k < 4; k++) {
            int idx = base + k * 8192;
            int j = idx >> 8, c = idx & 255;
            eWTb[idx] = f2bf(eW_ih0[c * MM + j]);
        }
    }
}

// ---------------- X0B[b][t][i] = bf16(input @ gW_ih0^T + gb_ih0 + gb_hh0) ----------------
__global__ void k_x0(const float* __restrict__ x, const float* __restrict__ Wih0,
                     const float* __restrict__ bih0, const float* __restrict__ bhh0,
                     unsigned short* __restrict__ X0B) {
    int row = blockIdx.x;           // b*SS + t
    int i = threadIdx.x;
    const float4* xr = (const float4*)(x + row * DD);
    const float4* wr = (const float4*)(Wih0 + i * DD);
    float a0 = 0.f, a1 = 0.f, a2 = 0.f, a3 = 0.f;
#pragma unroll 8
    for (int k = 0; k < DD / 4; k++) {
        float4 xv = xr[k]; float4 wv = wr[k];
        a0 += xv.x * wv.x; a1 += xv.y * wv.y; a2 += xv.z * wv.z; a3 += xv.w * wv.w;
    }
    X0B[row * HH + i] = f2bf(a0 + a1 + a2 + a3 + bih0[i] + bhh0[i]);
}

// ---------------- MFMA fragment loaders ----------------
__device__ __forceinline__ bf16x8 ldA(const unsigned short* __restrict__ pk, int ct, int kb, int lane) {
    return *(const bf16x8*)(pk + (((ct * 8 + kb) * 64 + lane) << 3));
}
__device__ __forceinline__ bf16x8 ldBf(const unsigned short* base, int row, int kb, int q) {
    return *(const bf16x8*)(base + ((row * ROWG + kb * 4 + q) << 3));
}

// ---------------- graph RNN: one WG per batch; CRITICAL-FIRST phase order ----------------
// Part 1: read h0[t-1] frags only -> acc + pAe/pBe MFMAs -> tanh -> write h0[t].
// Part 2: read h1[t-2] frags -> pAh/pBh -> tanh -> write h1[t-1] + gs. One barrier.
__global__ __launch_bounds__(512, 2) void k_graph_mfma(
    const unsigned short* __restrict__ X0B, const int* __restrict__ mask,
    const unsigned short* __restrict__ pk0,  // gW_hh0 packed
    const unsigned short* __restrict__ pk1,  // gW_ih1 packed
    const unsigned short* __restrict__ pk2,  // gW_hh1 packed
    const float* __restrict__ bih1, const float* __restrict__ bhh1,
    float* __restrict__ GS) {
    __shared__ alignas(16) unsigned short xs[SS * HH];   // 64 KB: X0 bf16
    __shared__ alignas(16) unsigned short gs[SS * HH];   // 64 KB: GS bf16
    __shared__ alignas(16) unsigned short h0b[2 * FB1];
    __shared__ alignas(16) unsigned short h1b[3 * FB1];
    __shared__ int lenS;

    int b = blockIdx.x;
    int tid = threadIdx.x;
    int wv = tid >> 6, lane = tid & 63;
    int q = lane >> 4, rr = lane & 15;
    int ct0 = 2 * wv;
    int m0 = 32 * wv + 4 * q;
    int g16off = (wv * 4 + q) << 3;

    { unsigned* p = (unsigned*)h0b; for (int i = tid; i < FB1; i += 512) p[i] = 0; }
    { unsigned* p = (unsigned*)h1b; for (int i = tid; i < 3 * FB1 / 2; i += 512) p[i] = 0; }
    {
        const uint4* s = (const uint4*)(X0B + b * SS * HH);
        uint4* d = (uint4*)xs;
        for (int i = tid; i < SS * HH / 8; i += 512) d[i] = s[i];
    }
    if (wv == 0) {
        int s = mask[b * SS + lane] + mask[b * SS + 64 + lane];
        for (int off = 32; off; off >>= 1) s += __shfl_xor(s, off);
        if (lane == 0) lenS = s;
    }
    bf16x8 a0[2][8], a1[2][8], a2[2][8];
#pragma unroll
    for (int kb = 0; kb < 8; kb++) {
        a0[0][kb] = ldA(pk0, ct0, kb, lane); a0[1][kb] = ldA(pk0, ct0 + 1, kb, lane);
        a1[0][kb] = ldA(pk1, ct0, kb, lane); a1[1][kb] = ldA(pk1, ct0 + 1, kb, lane);
        a2[0][kb] = ldA(pk2, ct0, kb, lane); a2[1][kb] = ldA(pk2, ct0 + 1, kb, lane);
    }
#pragma unroll
    for (int kb = 0; kb < 8; kb++) {
        asm volatile("" : "+v"(a0[0][kb]), "+v"(a0[1][kb]),
                          "+v"(a1[0][kb]), "+v"(a1[1][kb]),
                          "+v"(a2[0][kb]), "+v"(a2[1][kb]));
    }
    f32x4 b1A = *(const f32x4*)(bih1 + m0) + *(const f32x4*)(bhh1 + m0);
    f32x4 b1B = *(const f32x4*)(bih1 + m0 + 16) + *(const f32x4*)(bhh1 + m0 + 16);
    __syncthreads();
    int len = lenS;                 // WG-uniform, len >= 64
    bool w0l = (rr == 0);

    // ---- phase 0: h0[0] = tanh(x[0]) ----
    {
        ushort4 xa = *(const ushort4*)(xs + m0);
        ushort4 xb = *(const ushort4*)(xs + m0 + 16);
        if (w0l) {
            uint4 nv = { cvtpk(ftanh(bfs(xa.x)), ftanh(bfs(xa.y))),
                         cvtpk(ftanh(bfs(xa.z)), ftanh(bfs(xa.w))),
                         cvtpk(ftanh(bfs(xb.x)), ftanh(bfs(xb.y))),
                         cvtpk(ftanh(bfs(xb.z)), ftanh(bfs(xb.w))) };
            *(uint4*)(h0b + g16off) = nv;
        }
    }
    __syncthreads();

    // x prefetch for t=1
    ushort4 xcA = *(const ushort4*)(xs + 256 + m0);
    ushort4 xcB = *(const ushort4*)(xs + 256 + m0 + 16);

    // ---- main phases t=1..len-1: h0[t] (critical-first) then h1[t-1]; 1 barrier ----
    int ir = 2, iw = 0;
    for (int t = 1; t < len; t++) {
        const unsigned short* h0r = h0b + ((t - 1) & 1) * FB1;
        const unsigned short* h1r = h1b + ir * FB1;
        int tn = (t + 1 < SS) ? t + 1 : t;
        ushort4 xnA = *(const ushort4*)(xs + tn * 256 + m0);
        ushort4 xnB = *(const ushort4*)(xs + tn * 256 + m0 + 16);
        f32x4 accA0 = { bfs(xcA.x), bfs(xcA.y), bfs(xcA.z), bfs(xcA.w) };
        f32x4 accB0 = { bfs(xcB.x), bfs(xcB.y), bfs(xcB.z), bfs(xcB.w) };
        f32x4 accA1 = {0.f,0.f,0.f,0.f}, accB1 = {0.f,0.f,0.f,0.f};
        f32x4 pAe = b1A, pBe = b1B;
        // ---- part 1: consume h0[t-1] frags (8 reads), acc + L1-e MFMAs ----
#pragma unroll
        for (int kb = 0; kb < 4; kb++) {
            bf16x8 h = ldBf(h0r, 0, kb, q);
            accA0 = __builtin_amdgcn_mfma_f32_16x16x32_bf16(a0[0][kb], h, accA0, 0, 0, 0);
            accB0 = __builtin_amdgcn_mfma_f32_16x16x32_bf16(a0[1][kb], h, accB0, 0, 0, 0);
            pAe   = __builtin_amdgcn_mfma_f32_16x16x32_bf16(a1[0][kb], h, pAe, 0, 0, 0);
            pBe   = __builtin_amdgcn_mfma_f32_16x16x32_bf16(a1[1][kb], h, pBe, 0, 0, 0);
        }
#pragma unroll
        for (int kb = 4; kb < 8; kb++) {
            bf16x8 h = ldBf(h0r, 0, kb, q);
            accA1 = __builtin_amdgcn_mfma_f32_16x16x32_bf16(a0[0][kb], h, accA1, 0, 0, 0);
            accB1 = __builtin_amdgcn_mfma_f32_16x16x32_bf16(a0[1][kb], h, accB1, 0, 0, 0);
            pAe   = __builtin_amdgcn_mfma_f32_16x16x32_bf16(a1[0][kb], h, pAe, 0, 0, 0);
            pBe   = __builtin_amdgcn_mfma_f32_16x16x32_bf16(a1[1][kb], h, pBe, 0, 0, 0);
        }
        if (w0l) {
            f32x4 accA = accA0 + accA1, accB = accB0 + accB1;
            uint4 nv0 = { cvtpk(ftanh(accA[0]), ftanh(accA[1])), cvtpk(ftanh(accA[2]), ftanh(accA[3])),
                          cvtpk(ftanh(accB[0]), ftanh(accB[1])), cvtpk(ftanh(accB[2]), ftanh(accB[3])) };
            *(uint4*)(h0b + (t & 1) * FB1 + g16off) = nv0;
        }
        // ---- part 2: consume h1[t-2] frags (8 reads), L1-h MFMAs, finish h1[t-1] ----
        f32x4 pAh = {0.f,0.f,0.f,0.f}, pBh = {0.f,0.f,0.f,0.f};
#pragma unroll
        for (int kb = 0; kb < 8; kb++) {
            bf16x8 g = ldBf(h1r, 0, kb, q);
            pAh = __builtin_amdgcn_mfma_f32_16x16x32_bf16(a2[0][kb], g, pAh, 0, 0, 0);
            pBh = __builtin_amdgcn_mfma_f32_16x16x32_bf16(a2[1][kb], g, pBh, 0, 0, 0);
        }
        if (w0l) {
            f32x4 pA = pAe + pAh, pB = pBe + pBh;
            float eA[4], eB[4];
#pragma unroll
            for (int r = 0; r < 4; r++) { eA[r] = ftanh(pA[r]); eB[r] = ftanh(pB[r]); }
            uint4 nv1 = { cvtpk(eA[0], eA[1]), cvtpk(eA[2], eA[3]),
                          cvtpk(eB[0], eB[1]), cvtpk(eB[2], eB[3]) };
            *(uint4*)(h1b + iw * FB1 + g16off) = nv1;
            uint2 ga = { cvtpk(eA[0], eA[1]), cvtpk(eA[2], eA[3]) };
            uint2 gb = { cvtpk(eB[0], eB[1]), cvtpk(eB[2], eB[3]) };
            *(uint2*)(gs + (t - 1) * 256 + m0) = ga;
            *(uint2*)(gs + (t - 1) * 256 + m0 + 16) = gb;
        }
        __syncthreads();
        xcA = xnA; xcB = xnB;
        ir = (ir + 1 == 3) ? 0 : ir + 1;
        iw = (iw + 1 == 3) ? 0 : iw + 1;
    }

    // ---- tail: h1[len-1] -> gs[len-1] ----
    {
        const unsigned short* h0r = h0b + ((len - 1) & 1) * FB1;
        const unsigned short* h1r = h1b + ir * FB1;
        f32x4 pAe = b1A, pBe = b1B;
        f32x4 pAh = {0.f,0.f,0.f,0.f}, pBh = {0.f,0.f,0.f,0.f};
#pragma unroll
        for (int kb = 0; kb < 8; kb++) {
            bf16x8 h = ldBf(h0r, 0, kb, q);
            bf16x8 g = ldBf(h1r, 0, kb, q);
            pAe = __builtin_amdgcn_mfma_f32_16x16x32_bf16(a1[0][kb], h, pAe, 0, 0, 0);
            pBe = __builtin_amdgcn_mfma_f32_16x16x32_bf16(a1[1][kb], h, pBe, 0, 0, 0);
            pAh = __builtin_amdgcn_mfma_f32_16x16x32_bf16(a2[0][kb], g, pAh, 0, 0, 0);
            pBh = __builtin_amdgcn_mfma_f32_16x16x32_bf16(a2[1][kb], g, pBh, 0, 0, 0);
        }
        if (w0l) {
            f32x4 pA = pAe + pAh, pB = pBe + pBh;
            uint2 ga = { cvtpk(ftanh(pA[0]), ftanh(pA[1])), cvtpk(ftanh(pA[2]), ftanh(pA[3])) };
            uint2 gb = { cvtpk(ftanh(pB[0]), ftanh(pB[1])), cvtpk(ftanh(pB[2]), ftanh(pB[3])) };
            *(uint2*)(gs + (len - 1) * 256 + m0) = ga;
            *(uint2*)(gs + (len - 1) * 256 + m0 + 16) = gb;
        }
    }
    __syncthreads();
    // ---- flush gs -> GS (f32), zeros for t >= len ----
    {
        float* dst = GS + b * (SS * HH);
        const uint4* src = (const uint4*)gs;
        for (int i = tid; i < SS * HH / 8; i += 512) {
            int t = i >> 5;
            float4 f0 = {0.f,0.f,0.f,0.f}, f1 = {0.f,0.f,0.f,0.f};
            if (t < len) {
                uint4 v = src[i];
                f0 = float4{ bflo(v.x), bfhi(v.x), bflo(v.y), bfhi(v.y) };
                f1 = float4{ bflo(v.z), bfhi(v.z), bflo(v.w), bfhi(v.w) };
            }
            *(float4*)(dst + i * 8) = f0;
            *(float4*)(dst + i * 8 + 4) = f1;
        }
    }
}

// ---------------- edge RNN scan: MERGED phases + transposed red reduce ----------------
__global__ __launch_bounds__(512, 2) void k_edge_mfma(
    const float* __restrict__ GS,
    const unsigned short* __restrict__ pk0,  // eW_hh0 packed
    const unsigned short* __restrict__ pk1,  // eW_ih1 packed
    const unsigned short* __restrict__ pk2,  // eW_hh1 packed
    const unsigned short* __restrict__ pkh,  // head_W packed
    const unsigned short* __restrict__ pkd,  // dep_W packed
    const unsigned short* __restrict__ eWTb, // eW_ih0^T bf16 (128 x 256)
    const float* __restrict__ bih0, const float* __restrict__ bhh0,
    const float* __restrict__ bih1, const float* __restrict__ bhh1,
    const float* __restrict__ clsW, const float* __restrict__ clsB,
    const float* __restrict__ headB, const float* __restrict__ depB,
    float* __restrict__ arc, float* __restrict__ headO, float* __restrict__ depO) {
    __shared__ alignas(16) unsigned short h0f[2 * FBE];
    __shared__ alignas(16) unsigned short h1f[2 * FBE];
    __shared__ alignas(16) unsigned short gsf[FBE];      // GS init frags (for heads)
    __shared__ alignas(16) unsigned short ews[MM * HH];  // 64 KB
    __shared__ alignas(16) float red[GG][NW];            // transposed: row rr = 8 partials
    __shared__ float cws[HH];
    __shared__ float b1s[HH];
    __shared__ float arcb[GG][MM + 1];

    int tid = threadIdx.x;
    int wv = tid >> 6, lane = tid & 63;
    int q = lane >> 4, rr = lane & 15;
    int m0 = 32 * wv + 4 * q;
    int goff = (rr * ROWG + wv * 4 + q) << 3;
    int r0 = blockIdx.x * GG;

    // stage eWTb into LDS (64 KB coalesced)
    {
        const uint4* s = (const uint4*)eWTb;
        uint4* d = (uint4*)ews;
        for (int i = tid; i < MM * HH / 8; i += 512) d[i] = s[i];
    }
    // init: h0[-1]=h1[-1]=gsf (buf 1); zero buf 0 (phase-0 dummy h1[-2] reads)
    {
        int r = tid >> 5, g = tid & 31;           // g = kb*4 + qq
        int kb = g >> 2, qq = g & 3;
        int lo = kb * 32 + qq * 4;
        const float* gp = GS + (r0 + r) * HH + lo;
        float4 vlo = *(const float4*)gp;
        float4 vhi = *(const float4*)(gp + 16);
        uint4 pv = { cvtpk(vlo.x, vlo.y), cvtpk(vlo.z, vlo.w),
                     cvtpk(vhi.x, vhi.y), cvtpk(vhi.z, vhi.w) };
        int off = (r * ROWG + g) << 3;
        *(uint4*)(h0f + FBE + off) = pv;
        *(uint4*)(h1f + FBE + off) = pv;
        *(uint4*)(gsf + off) = pv;
        *(uint4*)(h1f + off) = uint4{0,0,0,0};
        *(uint4*)(h0f + off) = uint4{0,0,0,0};
    }
    if (tid < HH) {
        cws[tid] = clsW[tid];
        b1s[tid] = bih1[tid] + bhh1[tid];
    }
    // weights -> registers (192/lane), pinned
    bf16x8 a0[2][8], a1[2][8], a2[2][8];
#pragma unroll
    for (int kb = 0; kb < 8; kb++) {
        a0[0][kb] = ldA(pk0, 2 * wv, kb, lane); a0[1][kb] = ldA(pk0, 2 * wv + 1, kb, lane);
        a1[0][kb] = ldA(pk1, 2 * wv, kb, lane); a1[1][kb] = ldA(pk1, 2 * wv + 1, kb, lane);
        a2[0][kb] = ldA(pk2, 2 * wv, kb, lane); a2[1][kb] = ldA(pk2, 2 * wv + 1, kb, lane);
    }
#pragma unroll
    for (int kb = 0; kb < 8; kb++) {
        asm volatile("" : "+v"(a0[0][kb]), "+v"(a0[1][kb]),
                          "+v"(a1[0][kb]), "+v"(a1[1][kb]),
                          "+v"(a2[0][kb]), "+v"(a2[1][kb]));
    }
    // xw0 in registers (D-layout)
    f32x4 xw0A = *(const f32x4*)(bih0 + m0) + *(const f32x4*)(bhh0 + m0);
    f32x4 xw0B = *(const f32x4*)(bih0 + m0 + 16) + *(const f32x4*)(bhh0 + m0 + 16);
    float clsb = clsB[0];
    int srow = (r0 + tid) & 127;
    __syncthreads();

    for (int j = 0; j <= MM; j++) {
        const unsigned short* h0r = h0f + ((j + 1) & 1) * FBE;   // h0[j-1]
        const unsigned short* h1r = h1f + (j & 1) * FBE;         // h1[j-2]
        f32x4 acc0 = xw0A, acc1 = xw0B;                  // layer0[j]
        f32x4 p0 = *(const f32x4*)&b1s[m0];              // layer1[j-1]
        f32x4 p1 = *(const f32x4*)&b1s[m0 + 16];
#pragma unroll
        for (int kb = 0; kb < 8; kb++) {
            bf16x8 b0 = ldBf(h0r, rr, kb, q);            // shared: L0 + L1-e
            bf16x8 b1 = ldBf(h1r, rr, kb, q);
            acc0 = __builtin_amdgcn_mfma_f32_16x16x32_bf16(a0[0][kb], b0, acc0, 0, 0, 0);
            acc1 = __builtin_amdgcn_mfma_f32_16x16x32_bf16(a0[1][kb], b0, acc1, 0, 0, 0);
            p0   = __builtin_amdgcn_mfma_f32_16x16x32_bf16(a1[0][kb], b0, p0, 0, 0, 0);
            p1   = __builtin_amdgcn_mfma_f32_16x16x32_bf16(a1[1][kb], b0, p1, 0, 0, 0);
            p0   = __builtin_amdgcn_mfma_f32_16x16x32_bf16(a2[0][kb], b1, p0, 0, 0, 0);
            p1   = __builtin_amdgcn_mfma_f32_16x16x32_bf16(a2[1][kb], b1, p1, 0, 0, 0);
        }
        if (j > 0) {
            float e1a[4], e1b[4];
#pragma unroll
            for (int r = 0; r < 4; r++) { e1a[r] = ftanh(p0[r]); e1b[r] = ftanh(p1[r]); }
            // h1[j-1] frag write
            uint4 nv = { cvtpk(e1a[0], e1a[1]), cvtpk(e1a[2], e1a[3]),
                         cvtpk(e1b[0], e1b[1]), cvtpk(e1b[2], e1b[3]) };
            *(uint4*)(h1f + ((j + 1) & 1) * FBE + goff) = nv;
            // cls partial, reduce over q
            f32x4 cwA = *(const f32x4*)&cws[m0];
            f32x4 cwB = *(const f32x4*)&cws[m0 + 16];
            float part = cwA[0] * e1a[0] + cwA[1] * e1a[1] + cwA[2] * e1a[2] + cwA[3] * e1a[3]
                       + cwB[0] * e1b[0] + cwB[1] * e1b[1] + cwB[2] * e1b[2] + cwB[3] * e1b[3];
            part += __shfl_xor(part, 16);
            part += __shfl_xor(part, 32);
            if (lane < 16) red[lane][wv] = part;
        }
        __syncthreads();   // B1: red + h1[j-1] complete
        if (j > 0) {
            f32x4 r0v = *(const f32x4*)&red[rr][0];
            f32x4 r1v = *(const f32x4*)&red[rr][4];
            float s = clsb + r0v[0] + r0v[1] + r0v[2] + r0v[3]
                           + r1v[0] + r1v[1] + r1v[2] + r1v[3];
            float edge = fsigm(s);
            ushort4 ewcA = *(const ushort4*)(ews + (j - 1) * HH + m0);
            ushort4 ewcB = *(const ushort4*)(ews + (j - 1) * HH + m0 + 16);
            f32x4 ewA = { bfs(ewcA.x), bfs(ewcA.y), bfs(ewcA.z), bfs(ewcA.w) };
            f32x4 ewB = { bfs(ewcB.x), bfs(ewcB.y), bfs(ewcB.z), bfs(ewcB.w) };
            xw0A += edge * ewA;  acc0 += edge * ewA;     // linear fix-up for col j-1
            xw0B += edge * ewB;  acc1 += edge * ewB;
            if (tid < GG) arcb[tid][j - 1] = ((j - 1) < srow) ? edge : 0.f;
        }
        if (j < MM) {
            uint4 nv = { cvtpk(ftanh(acc0[0]), ftanh(acc0[1])), cvtpk(ftanh(acc0[2]), ftanh(acc0[3])),
                         cvtpk(ftanh(acc1[0]), ftanh(acc1[1])), cvtpk(ftanh(acc1[2]), ftanh(acc1[3])) };
            *(uint4*)(h0f + (j & 1) * FBE + goff) = nv;
        }
        __syncthreads();   // B2: h0[j] complete
    }
    // ---- flush arc buffer ----
    for (int i = tid; i < GG * MM; i += 512) {
        int row = i & 15, j = i >> 4;
        int sr = (r0 + row) & 127, bi = (r0 + row) >> 7;
        arc[bi * (MM * SS) + j * SS + sr] = arcb[row][j];
    }
    // ---- fused heads: elu(GS @ W^T + b) via MFMA on gsf (unroll 1 -> no reg blowup) ----
    {
        f32x4 hA = *(const f32x4*)(headB + m0);
        f32x4 hB = *(const f32x4*)(headB + m0 + 16);
        f32x4 dA = *(const f32x4*)(depB + m0);
        f32x4 dB = *(const f32x4*)(depB + m0 + 16);
#pragma unroll 1
        for (int kb = 0; kb < 8; kb++) {
            bf16x8 bg = ldBf(gsf, rr, kb, q);
            hA = __builtin_amdgcn_mfma_f32_16x16x32_bf16(ldA(pkh, 2 * wv, kb, lane), bg, hA, 0, 0, 0);
            hB = __builtin_amdgcn_mfma_f32_16x16x32_bf16(ldA(pkh, 2 * wv + 1, kb, lane), bg, hB, 0, 0, 0);
            dA = __builtin_amdgcn_mfma_f32_16x16x32_bf16(ldA(pkd, 2 * wv, kb, lane), bg, dA, 0, 0, 0);
            dB = __builtin_amdgcn_mfma_f32_16x16x32_bf16(ldA(pkd, 2 * wv + 1, kb, lane), bg, dB, 0, 0, 0);
        }
        int row = r0 + rr;
        f32x4 oA, oB, eA, eB;
#pragma unroll
        for (int r = 0; r < 4; r++) {
            oA[r] = (hA[r] > 0.f) ? hA[r] : (__expf(hA[r]) - 1.0f);
            oB[r] = (hB[r] > 0.f) ? hB[r] : (__expf(hB[r]) - 1.0f);
            eA[r] = (dA[r] > 0.f) ? dA[r] : (__expf(dA[r]) - 1.0f);
            eB[r] = (dB[r] > 0.f) ? dB[r] : (__expf(dB[r]) - 1.0f);
        }
        *(f32x4*)(headO + row * TT + m0) = oA;
        *(f32x4*)(headO + row * TT + m0 + 16) = oB;
        *(f32x4*)(depO + row * TT + m0) = eA;
        *(f32x4*)(depO + row * TT + m0 + 16) = eB;
    }
}

extern "C" void kernel_launch(void* const* d_in, const int* in_sizes, int n_in,
                              void* d_out, int out_size, void* d_ws, size_t ws_size,
                              hipStream_t stream) {
    const float* input  = (const float*)d_in[0];
    const int*   mask   = (const int*)d_in[2];
    const float* gW_ih0 = (const float*)d_in[5];
    const float* gW_hh0 = (const float*)d_in[6];
    const float* gb_ih0 = (const float*)d_in[7];
    const float* gb_hh0 = (const float*)d_in[8];
    const float* gW_ih1 = (const float*)d_in[9];
    const float* gW_hh1 = (const float*)d_in[10];
    const float* gb_ih1 = (const float*)d_in[11];
    const float* gb_hh1 = (const float*)d_in[12];
    const float* eW_ih0 = (const float*)d_in[13];
    const float* eW_hh0 = (const float*)d_in[14];
    const float* eb_ih0 = (const float*)d_in[15];
    const float* eb_hh0 = (const float*)d_in[16];
    const float* eW_ih1 = (const float*)d_in[17];
    const float* eW_hh1 = (const float*)d_in[18];
    const float* eb_ih1 = (const float*)d_in[19];
    const float* eb_hh1 = (const float*)d_in[20];
    const float* cls_W  = (const float*)d_in[21];
    const float* cls_b  = (const float*)d_in[22];
    const float* head_W = (const float*)d_in[23];
    const float* head_b = (const float*)d_in[24];
    const float* dep_W  = (const float*)d_in[25];
    const float* dep_b  = (const float*)d_in[26];

    float* out      = (float*)d_out;
    float* head_out = out;                 // 8*128*256
    float* dep_out  = out + 262144;
    float* arc_out  = out + 524288;        // 8*128*128

    char* ws = (char*)d_ws;
    unsigned short* X0B = (unsigned short*)ws;                 // 512 KB bf16 [b][t][i]
    float* GS  = (float*)(ws + (1 << 20));                     // 1 MB
    unsigned short* pk_g0 = (unsigned short*)(ws + (2 << 20)); // 128 KB each
    unsigned short* pk_g1 = pk_g0 + 65536;
    unsigned short* pk_g2 = pk_g0 + 2 * 65536;
    unsigned short* pk_e0 = pk_g0 + 3 * 65536;
    unsigned short* pk_e1 = pk_g0 + 4 * 65536;
    unsigned short* pk_e2 = pk_g0 + 5 * 65536;
    unsigned short* pk_h0 = pk_g0 + 6 * 65536;
    unsigned short* pk_h1 = pk_g0 + 7 * 65536;
    unsigned short* eWTb  = pk_g0 + 8 * 65536;                 // 64 KB bf16

    k_prep<<<288, 256, 0, stream>>>(gW_hh0, gW_ih1, gW_hh1, eW_hh0, eW_ih1, eW_hh1,
                                    head_W, dep_W, eW_ih0,
                                    pk_g0, pk_g1, pk_g2, pk_e0, pk_e1, pk_e2,
                                    pk_h0, pk_h1, eWTb);
    k_x0<<<1024, 256, 0, stream>>>(input, gW_ih0, gb_ih0, gb_hh0, X0B);
    k_graph_mfma<<<8, 512, 0, stream>>>(X0B, mask, pk_g0, pk_g1, pk_g2, gb_ih1, gb_hh1, GS);
    k_edge_mfma<<<64, 512, 0, stream>>>(GS, pk_e0, pk_e1, pk_e2, pk_h0, pk_h1, eWTb,
                                        eb_ih0, eb_hh0, eb_ih1, eb_hh1, cls_W, cls_b,
                                        head_b, dep_b, arc_out, head_out, dep_out);
}